// Round 13
// baseline (169.581 us; speedup 1.0000x reference)
//
#include <hip/hip_runtime.h>
#include <math.h>

#define N_ROWS   65536
#define DIM      256
#define KCODES   1024
#define Q_SIZE   (N_ROWS * DIM)          // 16777216
#define OUT_LOSS Q_SIZE
#define OUT_PERP (Q_SIZE + 1)
#define OUT_IDX  (Q_SIZE + 2)

// flag threshold in scaled-score units (s' = 2^20 * d2-units). Same as r8 (passed).
#define TAUP 200.0f

// ws layout (bytes)
#define WS_LOSS   0        // double
#define WS_RCNT   8        // int
#define WS_E2     16       // float[1024]  original units
#define WS_E2P    4112     // float[1024]  scaled by 2^20
#define WS_COUNTS 8208     // int[1024]
#define WS_IDX    12304    // int[65536]
#define WS_RLIST  274448   // int[65536]
#define WS_ET     536592   // float[262144]   E^T fp32 (refine)
#define WS_P      1585168  // _Float16[262144] packed f16(1024*E) per-wave linear

typedef _Float16 half8 __attribute__((ext_vector_type(8)));
typedef _Float16 half4 __attribute__((ext_vector_type(4)));
typedef float    f32x4 __attribute__((ext_vector_type(4)));

#define ROWB 528    // LDS bytes per X row: 512 (xh) + 16 pad
#define RPB  64     // rows per block

// k_main LDS carve: X 33792 | e2p 4096 = 37888 B (B in registers)
#define LDS_X  0
#define LDS_E2 33792

// ---------------------------------------------------------------------------
// prep: e2, e2p, Et (fp32 transpose, refine), packed P; zero accums.
// P layout: P[q][cb][kk][nt][lane][8 halfs] — per-wave linear B-frag stream.
// grid 1024 x 256
__global__ void k_prep(const float* __restrict__ E, float* __restrict__ e2,
                       float* __restrict__ e2p, float* __restrict__ Et,
                       _Float16* __restrict__ P,
                       int* __restrict__ counts, double* __restrict__ loss,
                       int* __restrict__ rcnt) {
    int b = blockIdx.x, t = threadIdx.x;
    __shared__ double red[256];
    float v = E[b * DIM + t];
    red[t] = (double)v * (double)v;

    {   // packed B-stream write
        int o   = b * 256 + t;
        int j    = o & 7;
        int lane = (o >> 3) & 63;
        int nt   = (o >> 9) & 3;
        int kk   = (o >> 11) & 7;
        int cbq  = o >> 14;            // 0..15
        int q = cbq >> 2, cb = cbq & 3;
        int code = q * 256 + cb * 64 + nt * 16 + (lane & 15);
        int d    = (lane >> 4) * 8 + kk * 32 + j;
        P[o] = (_Float16)(E[code * DIM + d] * 1024.0f);   // exact scaling, RN
    }

    __syncthreads();
    for (int s = 128; s > 0; s >>= 1) {
        if (t < s) red[t] += red[t + s];
        __syncthreads();
    }
    if (t == 0) { e2[b] = (float)red[0]; e2p[b] = (float)(red[0] * 1048576.0); }

    int o = b * 256 + t;
    int d = o >> 10, k = o & 1023;
    Et[o] = E[k * DIM + d];

    if (b < 4) counts[b * 256 + t] = 0;
    if (b == 0 && t == 0) { *loss = 0.0; *rcnt = 0; }
}

// ---------------------------------------------------------------------------
// main: MFMA ranking, single f16 product xh*Eh (numerics identical to r8-r12;
// cb-rotation reorders only WHICH code-block is processed when — kk order
// inside each cb unchanged, so accumulation order and scores are bit-equal).
// r13: per-block cb-level rotation of the B stream. r12 showed ~3200 cyc/step
// with all pipes idle: every block read the IDENTICAL packed address sequence
// in lock-step -> chip-wide L2-channel hotspot (~4096 txns piled on one
// channel per step). rot = blockIdx%4 (x 4 per-wave quarters) = 16 distinct
// streams. Register-staged B, 2-deep rotation, counted vmcnt(4) (r12).
// OCCUPANCY NOTE (r4-r7): never use a min-waves launch bound here (spills).
// grid 1024 x 256
__launch_bounds__(256)
__global__ void k_main(const float* __restrict__ X, const _Float16* __restrict__ P,
                       const float* __restrict__ e2p,
                       int* __restrict__ idx_ws, int* __restrict__ rlist,
                       int* __restrict__ rcnt) {
    __shared__ __align__(16) char sAll[37888];
    const int tid  = threadIdx.x;
    const int wid  = tid >> 6;
    const int lane = tid & 63;
    const int c16  = lane & 15;
    const int kg   = lane >> 4;
    const int rb   = blockIdx.x * RPB;
    const int rot  = blockIdx.x & 3;     // cb rotation (address decorrelation)

    char* sA = sAll + LDS_X;

    // ---- stage X -> f16 in LDS; stage e2p -> LDS ----
    {
        const float4* Xg = (const float4*)(X + (size_t)rb * DIM);
        #pragma unroll
        for (int it = 0; it < 16; ++it) {
            int f = it * 256 + tid;
            int row = f >> 6, d4 = f & 63;
            float4 v = Xg[(size_t)row * 64 + d4];
            half4 hh = {(_Float16)v.x, (_Float16)v.y, (_Float16)v.z, (_Float16)v.w};
            *(half4*)(sA + row * ROWB + d4 * 8) = hh;
        }
        ((float4*)(sAll + LDS_E2))[tid] = ((const float4*)e2p)[tid];
    }
    __syncthreads();   // drains staging vmem — in-loop vmcnt counts only B loads

    // per-wave contiguous B stream: 128 KB per quarter, lane offset 16B
    const char* gB = (const char*)P + (size_t)wid * 131072 + (size_t)lane * 16;
    // rotated step: sR(s) = ((s>>3 + rot)&3)*8 + (s&7)
#define SROT(s) (((((s) >> 3) + rot) & 3) * 8 + ((s) & 7))
#define GLOAD(dst, sR, nt)                                                    \
    asm volatile("global_load_dwordx4 %0, %1, off"                            \
                 : "=v"(dst)                                                  \
                 : "v"(gB + (size_t)(((sR) * 4 + (nt)) * 1024))               \
                 : "memory")

    half8 bA[4], bB[4], bC[4];
    {
        const int s0 = SROT(0), s1 = SROT(1);
        GLOAD(bA[0], s0, 0); GLOAD(bA[1], s0, 1); GLOAD(bA[2], s0, 2); GLOAD(bA[3], s0, 3);
        GLOAD(bB[0], s1, 0); GLOAD(bB[1], s1, 1); GLOAD(bB[2], s1, 2); GLOAD(bB[3], s1, 3);
    }

    int Abase[4];
    #pragma unroll
    for (int mt = 0; mt < 4; ++mt) Abase[mt] = (mt * 16 + c16) * ROWB + kg * 16;

    float tb1[16], tb2[16];
    int   ti1[16];
    #pragma unroll
    for (int i = 0; i < 16; ++i) { tb1[i] = 3.4e38f; tb2[i] = 3.4e38f; ti1[i] = 0; }

    const int cw = wid * 256;
    const float* sE2 = (const float*)(sAll + LDS_E2);

    f32x4 acc[4][4];

    #pragma unroll
    for (int s = 0; s < 32; ++s) {
        const int kk = s & 7;
        if (kk == 0) {
            #pragma unroll
            for (int mt = 0; mt < 4; ++mt)
                #pragma unroll
                for (int nt = 0; nt < 4; ++nt) acc[mt][nt] = 0.0f;
        }
        // wait for set sR(s) (issued 2 steps back). Outstanding entering step s:
        // sets for s, s+1 = 8 loads -> vmcnt(4) drains this step's. Last: 0.
        if (s == 31) { asm volatile("s_waitcnt vmcnt(0)" ::: "memory"); }
        else         { asm volatile("s_waitcnt vmcnt(4)" ::: "memory"); }
        __builtin_amdgcn_sched_barrier(0);

        // issue set for step s+2 early (T14)
        if (s < 30) {
            const int s2 = SROT(s + 2);
            GLOAD(bC[0], s2, 0); GLOAD(bC[1], s2, 1);
            GLOAD(bC[2], s2, 2); GLOAD(bC[3], s2, 3);
        }

        half8 ah[4];
        #pragma unroll
        for (int mt = 0; mt < 4; ++mt)
            ah[mt] = *(const half8*)(sA + Abase[mt] + kk * 64);

        #pragma unroll
        for (int mt = 0; mt < 4; ++mt) {
            acc[mt][0] = __builtin_amdgcn_mfma_f32_16x16x32_f16(ah[mt], bA[0], acc[mt][0], 0, 0, 0);
            acc[mt][1] = __builtin_amdgcn_mfma_f32_16x16x32_f16(ah[mt], bA[1], acc[mt][1], 0, 0, 0);
            acc[mt][2] = __builtin_amdgcn_mfma_f32_16x16x32_f16(ah[mt], bA[2], acc[mt][2], 0, 0, 0);
            acc[mt][3] = __builtin_amdgcn_mfma_f32_16x16x32_f16(ah[mt], bA[3], acc[mt][3], 0, 0, 0);
        }

        if (kk == 7) {
            // epilogue for the PHYSICAL cb we just finished: cbR = SROT(s)>>3
            const int cbR = ((s >> 3) + rot) & 3;
            const int cbase = cw + cbR * 64;
            const int c0 = cbase + c16;
            float e2v[4];
            #pragma unroll
            for (int nt = 0; nt < 4; ++nt) e2v[nt] = sE2[c0 + nt * 16];
            #pragma unroll
            for (int mt = 0; mt < 4; ++mt)
                #pragma unroll
                for (int nt = 0; nt < 4; ++nt) {
                    int code = cbase + nt * 16 + c16;
                    #pragma unroll
                    for (int r = 0; r < 4; ++r) {
                        float sc = fmaf(-2048.0f, acc[mt][nt][r], e2v[nt]);
                        int ix = mt * 4 + r;
                        tb2[ix] = __builtin_amdgcn_fmed3f(tb1[ix], tb2[ix], sc);
                        bool lt = sc < tb1[ix];
                        tb1[ix] = lt ? sc : tb1[ix];
                        ti1[ix] = lt ? code : ti1[ix];
                    }
                }
        }

        #pragma unroll
        for (int nt = 0; nt < 4; ++nt) { bA[nt] = bB[nt]; bB[nt] = bC[nt]; }
    }
#undef GLOAD
#undef SROT

    // ---- butterfly merge across the 16 col-lanes of each kg group ----
    #pragma unroll
    for (int ix = 0; ix < 16; ++ix) {
        float v1 = tb1[ix], v2 = tb2[ix];
        int   j1 = ti1[ix];
        #pragma unroll
        for (int m = 1; m < 16; m <<= 1) {
            float ov1 = __shfl_xor(v1, m, 64);
            int   oj1 = __shfl_xor(j1, m, 64);
            float ov2 = __shfl_xor(v2, m, 64);
            bool take = (ov1 < v1) || (ov1 == v1 && oj1 < j1);
            float losr = take ? v1 : ov1;
            v1 = take ? ov1 : v1;
            j1 = take ? oj1 : j1;
            v2 = fminf(fminf(v2, ov2), losr);
        }
        tb1[ix] = v1; tb2[ix] = v2; ti1[ix] = j1;
    }

    // ---- cross-wave merge via LDS (reuse sA region) ----
    __syncthreads();
    float* mB1 = (float*)sA;            // [64][4]
    float* mB2 = (float*)(sA + 1024);   // [64][4]
    int*   mI1 = (int*)(sA + 2048);     // [64][4]
    #pragma unroll
    for (int ix = 0; ix < 16; ++ix) {
        if (c16 == ix) {
            int row = (ix >> 2) * 16 + kg * 4 + (ix & 3);
            mB1[row * 4 + wid] = tb1[ix];
            mB2[row * 4 + wid] = tb2[ix];
            mI1[row * 4 + wid] = ti1[ix];
        }
    }
    __syncthreads();
    if (tid < RPB) {
        float m1 = 3.4e38f, m2 = 3.4e38f;
        int mi = 0;
        #pragma unroll
        for (int w = 0; w < 4; ++w) {
            float v = mB1[tid * 4 + w];
            int  id = mI1[tid * 4 + w];
            float u = mB2[tid * 4 + w];
            bool take = (v < m1) || (v == m1 && id < mi);
            float losr = take ? m1 : v;
            m1 = take ? v : m1;
            mi = take ? id : mi;
            m2 = fminf(fminf(m2, u), losr);
        }
        int g = rb + tid;
        idx_ws[g] = mi;
        if (m2 - m1 < TAUP) {
            int slot = atomicAdd(rcnt, 1);
            rlist[slot] = g;
        }
    }
}

// ---------------------------------------------------------------------------
// refine: exact reference-fp32 replication, 4 rows per Et sweep, d-loop
// unrolled x4, grid 1024. fp64 accumulation order per accumulator UNCHANGED.
// grid 1024 x 256
__launch_bounds__(256, 1)
__global__ void k_refine(const float* __restrict__ X, const float* __restrict__ Et,
                         const float* __restrict__ e2,
                         const int* __restrict__ rlist, const int* __restrict__ rcnt,
                         int* __restrict__ idx_ws) {
    __shared__ float xs[4][256];
    __shared__ float sbv[4][256];
    __shared__ int   sbi[4][256];
    __shared__ float x2s[4];
    __shared__ int   rows[4];
    const int cnt = *rcnt;
    const int t = threadIdx.x;
    for (int base = blockIdx.x * 4; base < cnt; base += gridDim.x * 4) {
        __syncthreads();
        if (t < 4) {
            int e = base + t;
            rows[t] = rlist[e < cnt ? e : (cnt - 1)];
        }
        __syncthreads();
        ((float4*)xs[t >> 6])[t & 63] =
            ((const float4*)(X + (size_t)rows[t >> 6] * DIM))[t & 63];
        __syncthreads();
        if (t < 4) {
            double s = 0.0;
            for (int d = 0; d < DIM; ++d) { double xv = (double)xs[t][d]; s += xv * xv; }
            x2s[t] = (float)s;
        }
        __syncthreads();

        double a0[4], a1[4], a2[4], a3[4];
        #pragma unroll
        for (int r = 0; r < 4; ++r) { a0[r] = 0.0; a1[r] = 0.0; a2[r] = 0.0; a3[r] = 0.0; }
        #pragma unroll 4
        for (int d = 0; d < DIM; ++d) {
            double e0 = (double)Et[d * KCODES + t];
            double e1 = (double)Et[d * KCODES + 256 + t];
            double e2d = (double)Et[d * KCODES + 512 + t];
            double e3 = (double)Et[d * KCODES + 768 + t];
            #pragma unroll
            for (int r = 0; r < 4; ++r) {
                double xv = (double)xs[r][d];
                a0[r] += xv * e0;
                a1[r] += xv * e1;
                a2[r] += xv * e2d;
                a3[r] += xv * e3;
            }
        }

        const float eA = e2[t], eB = e2[256 + t], eC = e2[512 + t], eD = e2[768 + t];
        #pragma unroll
        for (int r = 0; r < 4; ++r) {
            float best = 3.4e38f; int bk = 0;
            float x2 = x2s[r];
            { float d2 = fmaf(-2.f, (float)a0[r], x2 + eA); if (d2 < best) { best = d2; bk = t; } }
            { float d2 = fmaf(-2.f, (float)a1[r], x2 + eB); if (d2 < best) { best = d2; bk = 256 + t; } }
            { float d2 = fmaf(-2.f, (float)a2[r], x2 + eC); if (d2 < best) { best = d2; bk = 512 + t; } }
            { float d2 = fmaf(-2.f, (float)a3[r], x2 + eD); if (d2 < best) { best = d2; bk = 768 + t; } }
            sbv[r][t] = best; sbi[r][t] = bk;
        }
        __syncthreads();
        {
            const int w = t >> 6, lane = t & 63;
            float v = sbv[w][lane];     int id = sbi[w][lane];
            #pragma unroll
            for (int c = 1; c < 4; ++c) {
                float ov = sbv[w][lane + 64 * c]; int oi = sbi[w][lane + 64 * c];
                if (ov < v || (ov == v && oi < id)) { v = ov; id = oi; }
            }
            #pragma unroll
            for (int m = 1; m < 64; m <<= 1) {
                float ov = __shfl_xor(v, m, 64);
                int   oi = __shfl_xor(id, m, 64);
                if (ov < v || (ov == v && oi < id)) { v = ov; id = oi; }
            }
            if (lane == 0 && base + w < cnt) idx_ws[rows[w]] = id;
        }
    }
}

// ---------------------------------------------------------------------------
// out: quantized rows, index output, loss, histogram. One fp64 atomic/block.
// grid 1024 x 256
__launch_bounds__(256)
__global__ void k_out(const float* __restrict__ X, const float* __restrict__ E,
                      const int* __restrict__ idx_ws, float* __restrict__ out,
                      int* __restrict__ counts, double* __restrict__ loss) {
    const int tid = threadIdx.x;
    const int w = tid >> 6, lane = tid & 63;
    const int rbase = blockIdx.x * 64;
    double ls = 0.0;
    #pragma unroll 4
    for (int it = 0; it < 16; ++it) {
        const int row = rbase + it * 4 + w;
        const int k = idx_ws[row];
        float4 q = ((const float4*)(E + (size_t)k * DIM))[lane];
        float4 x = ((const float4*)(X + (size_t)row * DIM))[lane];
        ((float4*)(out + (size_t)row * DIM))[lane] = q;
        double d0 = (double)q.x - (double)x.x;
        double d1 = (double)q.y - (double)x.y;
        double d2 = (double)q.z - (double)x.z;
        double d3 = (double)q.w - (double)x.w;
        ls += d0 * d0 + d1 * d1 + d2 * d2 + d3 * d3;
        if (lane == 0) {
            atomicAdd(&counts[k], 1);
            out[OUT_IDX + row] = (float)k;
        }
    }
    __shared__ double red[256];
    red[tid] = ls;
    __syncthreads();
    for (int s = 128; s > 0; s >>= 1) {
        if (tid < s) red[tid] += red[tid + s];
        __syncthreads();
    }
    if (tid == 0) atomicAdd(loss, red[0]);
}

// ---------------------------------------------------------------------------
// fin: scalars
__global__ void k_fin(const int* __restrict__ counts, const double* __restrict__ loss,
                      float* __restrict__ out) {
    int t = threadIdx.x;
    __shared__ double red[256];
    double h = 0.0;
    #pragma unroll
    for (int i = 0; i < 4; ++i) {
        double p = (double)counts[t + i * 256] / (double)N_ROWS;
        h += p * log(p + 1e-10);
    }
    red[t] = h;
    __syncthreads();
    for (int s = 128; s > 0; s >>= 1) {
        if (t < s) red[t] += red[t + s];
        __syncthreads();
    }
    if (t == 0) {
        out[OUT_PERP] = (float)exp(-red[0]);
        out[OUT_LOSS] = (float)((*loss) / (double)Q_SIZE * 1.25);
    }
}

// ---------------------------------------------------------------------------
extern "C" void kernel_launch(void* const* d_in, const int* in_sizes, int n_in,
                              void* d_out, int out_size, void* d_ws, size_t ws_size,
                              hipStream_t stream) {
    (void)in_sizes; (void)n_in; (void)out_size; (void)ws_size;
    const float* X = (const float*)d_in[0];
    const float* E = (const float*)d_in[1];
    float* out = (float*)d_out;
    char* ws = (char*)d_ws;

    double*    loss   = (double*)(ws + WS_LOSS);
    int*       rcnt   = (int*)(ws + WS_RCNT);
    float*     e2     = (float*)(ws + WS_E2);
    float*     e2p    = (float*)(ws + WS_E2P);
    int*       counts = (int*)(ws + WS_COUNTS);
    int*       idx_ws = (int*)(ws + WS_IDX);
    int*       rlist  = (int*)(ws + WS_RLIST);
    float*     Et     = (float*)(ws + WS_ET);
    _Float16*  Pp     = (_Float16*)(ws + WS_P);

    k_prep<<<1024, 256, 0, stream>>>(E, e2, e2p, Et, Pp, counts, loss, rcnt);
    k_main<<<N_ROWS / RPB, 256, 0, stream>>>(X, Pp, e2p, idx_ws, rlist, rcnt);
    k_refine<<<1024, 256, 0, stream>>>(X, Et, e2, rlist, rcnt, idx_ws);
    k_out<<<1024, 256, 0, stream>>>(X, E, idx_ws, out, counts, loss);
    k_fin<<<1, 256, 0, stream>>>(counts, loss, out);
}